// Round 11
// baseline (6034.485 us; speedup 1.0000x reference)
//
#include <hip/hip_runtime.h>
#include <math.h>

#define Bsz 16384
#define Msz 512
#define Nsz 2048

typedef _Float16 half8 __attribute__((ext_vector_type(8)));
typedef _Float16 half4 __attribute__((ext_vector_type(4)));
typedef _Float16 half2v __attribute__((ext_vector_type(2)));
typedef float floatx16 __attribute__((ext_vector_type(16)));
typedef unsigned int uint;

struct HL { _Float16 h, l; };
__device__ __forceinline__ HL split1(float x) {
    HL r;
    r.h = (_Float16)x;
    r.l = (_Float16)(x - (float)r.h);   // exact residual (two-term split)
    return r;
}
__device__ __forceinline__ uint packHL(float x) {
    HL s = split1(x);
    return (uint)__builtin_bit_cast(unsigned short, s.h)
         | ((uint)__builtin_bit_cast(unsigned short, s.l) << 16);
}
__device__ __forceinline__ float unpackHL(uint w) {
    half2v p = __builtin_bit_cast(half2v, w);
    return (float)p.x + (float)p.y;
}

// async global->LDS, 16B per lane. LDS dest = wave-uniform base + lane*16.
__device__ __forceinline__ void gl_lds16(const _Float16* g, _Float16* l) {
    __builtin_amdgcn_global_load_lds(
        (const __attribute__((address_space(1))) unsigned int*)g,
        (__attribute__((address_space(3))) unsigned int*)l, 16, 0, 0);
}

// fragment-permuted layout (32x32x16 MFMA): element (r,k) of [R][K] at
// ((r>>5)*(K/16) + (k>>4))*512 + (r&31)*16 + (k&15)   [halves]

// zero 19*Bsz floats (t2 slabs 1..9 + na2 slabs 0..9, contiguous)
__global__ __launch_bounds__(256) void zero_kernel(float4* __restrict__ p) {
    p[blockIdx.x * 256 + threadIdx.x] = make_float4(0.f, 0.f, 0.f, 0.f);
}

// iter-0: v = batch -> single f16 permuted plane; t2s[0][b] = sum(v^2) (fp32).
__global__ __launch_bounds__(256) void init_kernel(const float* __restrict__ batch,
        _Float16* __restrict__ vh, float* __restrict__ t2) {
    const int wave = threadIdx.x >> 6;
    const int lane = threadIdx.x & 63;
    const int b = (blockIdx.x << 2) + wave;
    const float* row = batch + (size_t)b * Msz + lane * 8;
    float4 a = *(const float4*)row;
    float4 c = *(const float4*)(row + 4);
    half8 h;
    h[0] = (_Float16)a.x; h[1] = (_Float16)a.y;
    h[2] = (_Float16)a.z; h[3] = (_Float16)a.w;
    h[4] = (_Float16)c.x; h[5] = (_Float16)c.y;
    h[6] = (_Float16)c.z; h[7] = (_Float16)c.w;
    const size_t off = ((size_t)(b >> 5) * 32 + (lane >> 1)) * 512
                     + ((b & 31) << 4) + ((lane & 1) << 3);
    *(half8*)(vh + off) = h;
    float s = a.x*a.x + a.y*a.y + a.z*a.z + a.w*a.w
            + c.x*c.x + c.y*c.y + c.z*c.z + c.w*c.w;
#pragma unroll
    for (int off2 = 32; off2 > 0; off2 >>= 1) s += __shfl_down(s, off2);
    if (lane == 0) t2[b] = s;
}

// One-time: D [M][N] fp32 -> Dperm hi/lo  (gemm2 B: r=m, k=n, K=2048)
//                        and Dtperm hi/lo (gemm1 B: r=n, k=m, K=512)
__global__ __launch_bounds__(256) void convD_kernel(const float* __restrict__ D,
        _Float16* __restrict__ Dph, _Float16* __restrict__ Dpl,
        _Float16* __restrict__ Dtph, _Float16* __restrict__ Dtpl) {
    __shared__ float T[64][65];
    const int t = threadIdx.x;
    const int tx = t & 15, ty = t >> 4;
    const int n0 = blockIdx.x << 6, m0 = blockIdx.y << 6;
#pragma unroll
    for (int q = 0; q < 4; ++q) {
        const int mr = m0 + (ty << 2) + q;
        const int nc = n0 + (tx << 2);
        float4 d = *(const float4*)(D + (size_t)mr * Nsz + nc);
        half4 h, l;
        HL s0 = split1(d.x), s1 = split1(d.y), s2 = split1(d.z), s3 = split1(d.w);
        h[0] = s0.h; l[0] = s0.l; h[1] = s1.h; l[1] = s1.l;
        h[2] = s2.h; l[2] = s2.l; h[3] = s3.h; l[3] = s3.l;
        const size_t o2 = ((size_t)(mr >> 5) * 128 + (nc >> 4)) * 512
                        + ((mr & 31) << 4) + (nc & 15);
        *(half4*)(Dph + o2) = h;
        *(half4*)(Dpl + o2) = l;
        T[(tx << 2) + 0][(ty << 2) + q] = d.x;
        T[(tx << 2) + 1][(ty << 2) + q] = d.y;
        T[(tx << 2) + 2][(ty << 2) + q] = d.z;
        T[(tx << 2) + 3][(ty << 2) + q] = d.w;
    }
    __syncthreads();
#pragma unroll
    for (int q = 0; q < 4; ++q) {
        const int nr = n0 + (ty << 2) + q;
        const int mc = m0 + (tx << 2);
        float4 d = make_float4(T[(ty << 2) + q][tx << 2],
                               T[(ty << 2) + q][(tx << 2) + 1],
                               T[(ty << 2) + q][(tx << 2) + 2],
                               T[(ty << 2) + q][(tx << 2) + 3]);
        half4 h, l;
        HL s0 = split1(d.x), s1 = split1(d.y), s2 = split1(d.z), s3 = split1(d.w);
        h[0] = s0.h; l[0] = s0.l; h[1] = s1.h; l[1] = s1.l;
        h[2] = s2.h; l[2] = s2.l; h[3] = s3.h; l[3] = s3.l;
        const size_t o1 = ((size_t)(nr >> 5) * 32 + (mc >> 4)) * 512
                        + ((nr & 31) << 4) + (mc & 15);
        *(half4*)(Dtph + o1) = h;
        *(half4*)(Dtpl + o1) = l;
    }
}

// gemm1: alpha = relu((first?0:alpha) + beta*(v@D) - t[b]); fused na2 atomic.
// Round-9 proven structure; occupancy raised to 6 blocks/CU (24KB LDS x 6 = 144KB).
__global__ __launch_bounds__(256, 6) void gemm1_kernel(
        const _Float16* __restrict__ Av,
        const _Float16* __restrict__ Bth, const _Float16* __restrict__ Btl,
        const float* __restrict__ t2,
        uint* __restrict__ alphaP,
        float* __restrict__ na2,
        const float* __restrict__ beta_p, const float* __restrict__ gamma_p,
        int first, int last) {
    __shared__ _Float16 lds[12288];   // 24KB: A | Bh | Bl, 4096 halves each

    const int tid = threadIdx.x;
    const int wave = tid >> 6, lane = tid & 63;
    const int wy = wave >> 1, wx = wave & 1;
    const int ln = lane & 31, lh = lane >> 5;
    const int bid = blockIdx.x;
    const int b0 = (bid & 127) << 7;    // row-tile sharers (stride-128 bids) -> same XCD
    const int n0 = (bid >> 7) << 7;
    const int R0 = b0 >> 5, C0 = n0 >> 5;

    floatx16 acc[2][2] = {};

    // staging: wave0 -> A plane, wave1 -> Bh, wave2 -> Bl, wave3 idle
    const _Float16* gsrc =
        (wave == 0) ? Av + (size_t)R0 * 32 * 512 :
        (wave == 1) ? Bth + (size_t)C0 * 32 * 512 :
                      Btl + (size_t)C0 * 32 * 512;
    gsrc += lane * 8;                    // 16B per lane
    _Float16* lplane = lds + wave * 4096;

    const int ro = ln * 16 + lh * 8;     // in-fragment lane offset (halves)

    for (int c = 0; c < 16; ++c) {
        __syncthreads();                 // previous chunk's frag reads done
        if (wave < 3) {
#pragma unroll
            for (int f = 0; f < 8; ++f) {    // frag (rtile i = f>>1, ktile j = f&1)
                const int i = f >> 1, j = f & 1;
                gl_lds16(gsrc + (((size_t)i * 32 + 2 * c + j) << 9), lplane + (f << 9));
            }
        }
        __builtin_amdgcn_s_waitcnt(0);   // drain this wave's DMA
        __syncthreads();                 // all planes staged

#pragma unroll
        for (int ks = 0; ks < 2; ++ks) {
            half8 fa[2], fbh[2], fbl[2];
#pragma unroll
            for (int i = 0; i < 2; ++i) {
                const int sa = (((wy * 2 + i) << 1) + ks) << 9;
                const int sb = (((wx * 2 + i) << 1) + ks) << 9;
                fa[i]  = *(const half8*)(lds + sa + ro);
                fbh[i] = *(const half8*)(lds + 4096 + sb + ro);
                fbl[i] = *(const half8*)(lds + 8192 + sb + ro);
            }
#pragma unroll
            for (int j = 0; j < 2; ++j)
#pragma unroll
                for (int i = 0; i < 2; ++i) {
                    acc[i][j] = __builtin_amdgcn_mfma_f32_32x32x16_f16(fa[i], fbh[j], acc[i][j], 0, 0, 0);
                    acc[i][j] = __builtin_amdgcn_mfma_f32_32x32x16_f16(fa[i], fbl[j], acc[i][j], 0, 0, 0);
                }
        }
    }

    const float beta = beta_p[0];
    const float tc = gamma_p[0] * 0.044194173824159216f;   // gamma / sqrt(512)
#pragma unroll
    for (int i = 0; i < 2; ++i) {
#pragma unroll
        for (int reg = 0; reg < 16; ++reg) {
            const int rr = (reg & 3) + 8 * (reg >> 2) + 4 * lh;   // 0..31
            const int b = b0 + wy * 64 + i * 32 + rr;
            const float tb = tc * sqrtf(t2[b]);
            uint* arow = alphaP + (size_t)b * Nsz + n0 + wx * 64 + ln;
            float s = 0.f;
#pragma unroll
            for (int j = 0; j < 2; ++j) {
                float z = first ? 0.f : unpackHL(arow[j * 32]);
                float val = fmaxf(fmaf(beta, acc[i][j][reg], z) - tb, 0.f);
                if (last) ((float*)arow)[j * 32] = val;   // final fp32, same 4-B slot
                else      arow[j * 32] = packHL(val);
                s = fmaf(val, val, s);
            }
            s += __shfl_down(s, 16, 32);
            s += __shfl_down(s, 8, 32);
            s += __shfl_down(s, 4, 32);
            s += __shfl_down(s, 2, 32);
            s += __shfl_down(s, 1, 32);
            if (ln == 0) atomicAdd(&na2[b], s);
        }
    }
}

// gemm2: v = y - beta*(alpha@D^T) + beta/512*sqrt(na2[b])*v_old; fused t2 atomic.
// Retiled 64x128 (1024 blocks = 4/CU). A = alpha_hi staged via regs+perm+ds_write;
// B = D hi/lo via global_load_lds (4 frags/wave). Round-9 barrier skeleton.
__global__ __launch_bounds__(256, 4) void gemm2_kernel(
        const uint* __restrict__ alphaP,
        const _Float16* __restrict__ Bh, const _Float16* __restrict__ Bl,
        const float* __restrict__ na2,
        const float* __restrict__ y,
        _Float16* __restrict__ vh,
        float* __restrict__ t2,
        const float* __restrict__ beta_p) {
    __shared__ _Float16 lds[10240];   // 20KB: A(4 frags) | Bh(8) | Bl(8)

    const int tid = threadIdx.x;
    const int wave = tid >> 6, lane = tid & 63;
    const int wy = wave >> 1, wx = wave & 1;
    const int ln = lane & 31, lh = lane >> 5;
    const int bid = blockIdx.x;
    const int b0 = (bid & 255) << 6;    // 256 row-tiles; sharers (stride-256) -> same XCD
    const int m0 = (bid >> 8) << 7;     // 4 col-tiles
    const int C0 = m0 >> 5;

    floatx16 acc[2] = {};               // j = 0,1 (two 32-col tiles)

    // A staging: thread (srow 0..63, skq word-offset {0,8,16,24})
    const int srow = tid >> 2;
    const int skq  = (tid & 3) << 3;
    const uint* apP = alphaP + (size_t)(b0 + srow) * Nsz + skq;
    const int awOff = (((srow >> 5) << 1) + (skq >> 4)) * 512
                    + ((srow & 31) << 4) + (skq & 15);

    // B staging via gl_lds: 16 frags, 4 per wave
    const _Float16* baseBh = Bh + (size_t)C0 * 128 * 512 + lane * 8;
    const _Float16* baseBl = Bl + (size_t)C0 * 128 * 512 + lane * 8;

    const int ro = ln * 16 + lh * 8;

    uint4 ra0 = *(const uint4*)(apP);
    uint4 ra1 = *(const uint4*)(apP + 4);

    for (int c = 0; c < 64; ++c) {
        // extract hi (low16s) of the 8 packed words
        uint4 ha;
        ha.x = __builtin_amdgcn_perm(ra0.y, ra0.x, 0x05040100u);
        ha.y = __builtin_amdgcn_perm(ra0.w, ra0.z, 0x05040100u);
        ha.z = __builtin_amdgcn_perm(ra1.y, ra1.x, 0x05040100u);
        ha.w = __builtin_amdgcn_perm(ra1.w, ra1.z, 0x05040100u);

        // prefetch next chunk's A regs (completes during barrier+MFMA span)
        if (c < 63) {
            const uint* nx = apP + (size_t)(c + 1) * 32;
            ra0 = *(const uint4*)(nx);
            ra1 = *(const uint4*)(nx + 4);
        }

        __syncthreads();                 // previous chunk's frag reads done
#pragma unroll
        for (int q = 0; q < 4; ++q) {
            const int f = wave * 4 + q;  // 0..15: plane p = f>>3, slot j = f&7
            const int p = f >> 3, j = f & 7;
            const int i = j >> 1, k2 = j & 1;
            const _Float16* gp = p ? baseBl : baseBh;
            gl_lds16(gp + (((size_t)i * 128 + 2 * c + k2) << 9),
                     lds + 2048 + p * 4096 + (j << 9));
        }
        *(uint4*)(lds + awOff) = ha;
        __builtin_amdgcn_s_waitcnt(0);
        __syncthreads();

#pragma unroll
        for (int ks = 0; ks < 2; ++ks) {
            half8 fa, fbh[2], fbl[2];
            fa = *(const half8*)(lds + (((wy << 1) + ks) << 9) + ro);
#pragma unroll
            for (int j = 0; j < 2; ++j) {
                const int sb = (((wx * 2 + j) << 1) + ks) << 9;
                fbh[j] = *(const half8*)(lds + 2048 + sb + ro);
                fbl[j] = *(const half8*)(lds + 6144 + sb + ro);
            }
#pragma unroll
            for (int j = 0; j < 2; ++j) {
                acc[j] = __builtin_amdgcn_mfma_f32_32x32x16_f16(fa, fbh[j], acc[j], 0, 0, 0);
                acc[j] = __builtin_amdgcn_mfma_f32_32x32x16_f16(fa, fbl[j], acc[j], 0, 0, 0);
            }
        }
    }

    const float beta = beta_p[0];
#pragma unroll
    for (int reg = 0; reg < 16; ++reg) {
        const int rr = (reg & 3) + 8 * (reg >> 2) + 4 * lh;
        const int b = b0 + wy * 32 + rr;
        const float cb = beta * (1.0f / 512.0f) * sqrtf(na2[b]);
        float s = 0.f;
#pragma unroll
        for (int j = 0; j < 2; ++j) {
            const int m = m0 + wx * 64 + j * 32 + ln;
            const size_t po = ((size_t)(b >> 5) * 32 + (m >> 4)) * 512
                            + ((b & 31) << 4) + (m & 15);
            const size_t yi = (size_t)b * Msz + m;
            float vold = (float)vh[po];
            float val = y[yi] - beta * acc[j][reg] + cb * vold;
            vh[po] = (_Float16)val;
            s = fmaf(val, val, s);
        }
        s += __shfl_down(s, 16, 32);
        s += __shfl_down(s, 8, 32);
        s += __shfl_down(s, 4, 32);
        s += __shfl_down(s, 2, 32);
        s += __shfl_down(s, 1, 32);
        if (ln == 0) atomicAdd(&t2[b], s);
    }
}

extern "C" void kernel_launch(void* const* d_in, const int* in_sizes, int n_in,
                              void* d_out, int out_size, void* d_ws, size_t ws_size,
                              hipStream_t stream) {
    (void)in_sizes; (void)n_in; (void)out_size; (void)ws_size;
    const float* batch   = (const float*)d_in[0];   // [B, M]
    const float* D       = (const float*)d_in[1];   // [M, N]
    const float* gamma_p = (const float*)d_in[2];   // scalar
    const float* beta_p  = (const float*)d_in[3];   // scalar

    uint* alphaP = (uint*)d_out;    // packed hi/lo per element (plain layout); fp32 after final iter

    // workspace (~27 MB)
    _Float16* vh   = (_Float16*)d_ws;               // [B*M] permuted, single plane
    _Float16* Dph  = vh + (size_t)Bsz * Msz;        // [M*N] permuted (gemm2 B)
    _Float16* Dpl  = Dph + (size_t)Msz * Nsz;
    _Float16* Dtph = Dpl + (size_t)Msz * Nsz;       // [N*M] permuted (gemm1 B)
    _Float16* Dtpl = Dtph + (size_t)Msz * Nsz;
    float*    t2s  = (float*)(Dtpl + (size_t)Msz * Nsz);   // [10][Bsz] sum v^2
    float*    na2s = t2s + 10 * Bsz;                        // [10][Bsz] sum alpha^2

    // zero t2 slabs 1..9 + na2 slabs 0..9 (contiguous 19*Bsz floats)
    zero_kernel<<<19 * Bsz / 1024, 256, 0, stream>>>((float4*)(t2s + Bsz));
    convD_kernel<<<dim3(Nsz / 64, Msz / 64), 256, 0, stream>>>(D, Dph, Dpl, Dtph, Dtpl);
    init_kernel<<<Bsz / 4, 256, 0, stream>>>(batch, vh, t2s);   // writes t2 slab 0

    for (int it = 0; it < 10; ++it) {
        gemm1_kernel<<<2048, 256, 0, stream>>>(vh, Dtph, Dtpl,
                                               t2s + (size_t)it * Bsz,
                                               alphaP,
                                               na2s + (size_t)it * Bsz,
                                               beta_p, gamma_p,
                                               it == 0 ? 1 : 0, it == 9 ? 1 : 0);
        if (it < 9) {   // last iteration's new_v is unused by the reference output
            gemm2_kernel<<<1024, 256, 0, stream>>>(alphaP, Dph, Dpl,
                                                   na2s + (size_t)it * Bsz,
                                                   batch, vh,
                                                   t2s + (size_t)(it + 1) * Bsz,
                                                   beta_p);
        }
    }
}